// Round 8
// baseline (387.751 us; speedup 1.0000x reference)
//
#include <hip/hip_runtime.h>
#include <hip/hip_bf16.h>
#include <cstdint>
#include <cstddef>

// Problem dims
#define B_N   64
#define T_N   500
#define K_IN  1250
#define KP    1280          // K padded to multiple of 32
#define N_H   512
#define M_N   32000

// GEMM1 tiling: 128 x 256 tile, 4 waves (2x2), wave tile 64x128
#define BM 128
#define BN 256
#define BK 32
#define NT (KP / BK)        // 40
#define XROWB (KP / 8)      // 160 bytes of bits per row

typedef __attribute__((ext_vector_type(8))) short bf16x8;  // 8 bf16 = 4 VGPRs
typedef __attribute__((ext_vector_type(4))) float f32x4;   // MFMA acc

#define DECAY_SR  0.9048374180359595732f   // exp(-1/10)
#define DECAY_REF 0.3678794411714423216f   // exp(-1)
#define THETA 10.0f

__device__ __forceinline__ unsigned short f2bf(float f) {
  __hip_bfloat16 h = __float2bfloat16(f);          // RNE
  return *reinterpret_cast<unsigned short*>(&h);
}
__device__ __forceinline__ float bf2f(unsigned short s) {
  union { uint32_t u; float f; } v; v.u = ((uint32_t)s) << 16; return v.f;
}

// ---------------------------------------------------------------------------
// Pre-pass A: bitpack X (binary spikes) -> Xb [32000][160B].
// ---------------------------------------------------------------------------
__global__ __launch_bounds__(256) void xpack_kernel(const float* __restrict__ X,
                                                    unsigned long long* __restrict__ Xb64) {
  int gw   = (blockIdx.x * 256 + threadIdx.x) >> 6;   // 0..31999 = row
  int lane = threadIdx.x & 63;
  const float* xr = X + (size_t)gw * K_IN;
  unsigned long long* out = Xb64 + (size_t)gw * (XROWB / 8);
  #pragma unroll
  for (int wd = 0; wd < 20; ++wd) {
    int k = wd * 64 + lane;
    float v = (k < K_IN) ? xr[k] : 0.f;
    unsigned long long m = __ballot(v > 0.5f);
    if (lane == 0) out[wd] = m;
  }
}

// ---------------------------------------------------------------------------
// Pre-pass B: W1 (512x1250 fp32) -> W1b (512x1280 bf16, zero-padded tail).
// ---------------------------------------------------------------------------
__global__ __launch_bounds__(256) void w1cvt_kernel(const float* __restrict__ W1,
                                                    short* __restrict__ W1b) {
  int k = blockIdx.x * 256 + threadIdx.x;   // 0..1279
  int n = blockIdx.y;                        // 0..511
  float v = (k < K_IN) ? W1[(size_t)n * K_IN + k] : 0.f;
  W1b[(size_t)n * KP + k] = (short)f2bf(v);
}

// ---------------------------------------------------------------------------
// GEMM1: U1[m][n] = sum_k X[m][k] * W1[n][k]
// Counted-vmcnt pipeline (T4): per K-step
//   { compute(t); lgkmcnt(0); s_barrier; stage(t+2)->buf[t&1] [5 DMA];
//     vmcnt(5) (tail: 0); s_barrier }
// ALL K-loop global traffic is global_load_lds (B: 4x16B/wave; A-bits:
// 1x4B/lane, lanes<32) -> no compiler VMEM in-loop, hand counts hold.
// A-frag: ds_read_b32 word (4-way broadcast) -> bfe byte -> VALU expand to
// 8 bf16{0,1} (no LUT). B swizzle slot'=slot^((row>>1)&3) (verified 0-conflict).
// LDS 33KB, VGPR ~132 -> ~3 blocks/CU.
// k-pairing: k = (lane>>4)*8 + elem, identical A and B (layout-agnostic).
// ---------------------------------------------------------------------------
__global__ __launch_bounds__(256) void gemm1_kernel(const unsigned char* __restrict__ Xb,
                                                    const short* __restrict__ W1b,
                                                    unsigned short* __restrict__ U1) {
  __shared__ short Bs[2][BN * BK];        // 2 x 16 KiB
  __shared__ unsigned int Ab[2][BM];      // 2 x 512 B  (word t of each row's bits)
  const int tid  = threadIdx.x;
  const int bn   = blockIdx.x * BN;       // n-block fastest (X-strip sharers adjacent)
  const int bm   = blockIdx.y * BM;
  const int w    = tid >> 6;
  const int lane = tid & 63;
  const int wr   = w >> 1;                // m half
  const int wc   = w & 1;                 // n half
  const int lrow = lane & 15;
  const int lgrp = lane >> 4;
  const int lsw  = lgrp ^ ((lrow >> 1) & 3);

  f32x4 acc[4][8];
  #pragma unroll
  for (int i = 0; i < 4; ++i)
    #pragma unroll
    for (int j = 0; j < 8; ++j)
      acc[i][j] = (f32x4){0.f, 0.f, 0.f, 0.f};

  const int brow16 = lane >> 2;
  const int bslp   = lane & 3;

  auto stage = [&](int buf, int t) {      // 5 DMA per wave, uniform
    int k0 = t * BK;
    #pragma unroll
    for (int c = 0; c < 4; ++c) {
      int ch = w * 4 + c;                         // 0..15
      int nl = ch * 16 + brow16;                  // local col
      int ss = bslp ^ ((nl >> 1) & 3);            // source slot (pre-swizzle)
      const short* src = W1b + (size_t)(bn + nl) * KP + k0 + ss * 8;
      __builtin_amdgcn_global_load_lds(
          (const __attribute__((address_space(1))) void*)src,
          (__attribute__((address_space(3))) void*)&Bs[buf][ch * 16 * BK], 16, 0, 0);
    }
    // A bits: wave w stages rows [w*32, w*32+32), 4B per lane (lanes 0..31)
    if (lane < 32) {
      const unsigned char* srcA = Xb + (size_t)(bm + w * 32 + lane) * XROWB + t * 4;
      __builtin_amdgcn_global_load_lds(
          (const __attribute__((address_space(1))) void*)srcA,
          (__attribute__((address_space(3))) void*)&Ab[buf][w * 32], 4, 0, 0);
    }
  };

  // prologue: tiles 0 and 1 in flight, then full drain once
  stage(0, 0);
  stage(1, 1);
  __syncthreads();

  for (int t = 0; t < NT; ++t) {
    const int pb = t & 1;
    // ---- compute(t) ----
    unsigned int aw[4];
    #pragma unroll
    for (int i = 0; i < 4; ++i)
      aw[i] = Ab[pb][wr * 64 + i * 16 + lrow];    // 4-way same-addr broadcast
    bf16x8 bv[8];
    #pragma unroll
    for (int j = 0; j < 8; ++j) {
      int r = wc * 128 + j * 16 + lrow;
      bv[j] = *(const bf16x8*)&Bs[pb][r * BK + lsw * 8];
    }
    bf16x8 af[4];
    #pragma unroll
    for (int i = 0; i < 4; ++i) {
      unsigned int b = (aw[i] >> (lgrp * 8)) & 0xFFu;
      #pragma unroll
      for (int e = 0; e < 8; ++e)
        af[i][e] = (short)(((b >> e) & 1u) * 0x3F80u);
    }
    #pragma unroll
    for (int i = 0; i < 4; ++i)
      #pragma unroll
      for (int j = 0; j < 8; ++j)
        acc[i][j] = __builtin_amdgcn_mfma_f32_16x16x32_bf16(af[i], bv[j], acc[i][j], 0, 0, 0);

    // ---- wave's own LDS reads complete before others may overwrite ----
    asm volatile("s_waitcnt lgkmcnt(0)" ::: "memory");
    __builtin_amdgcn_s_barrier();
    // ---- stage t+2 into the buffer just freed; counted wait for t+1 ----
    if (t + 2 < NT) {
      stage(pb, t + 2);
      asm volatile("s_waitcnt vmcnt(5)" ::: "memory");
    } else {
      asm volatile("s_waitcnt vmcnt(0)" ::: "memory");
    }
    __builtin_amdgcn_s_barrier();
  }

  // ---- epilogue: C/D map col=lane&15, row=(lane>>4)*4+reg; U1 bf16 ----
  #pragma unroll
  for (int i = 0; i < 4; ++i) {
    int row0 = bm + wr * 64 + i * 16 + lgrp * 4;
    #pragma unroll
    for (int j = 0; j < 8; ++j) {
      int col = bn + wc * 128 + j * 16 + lrow;
      #pragma unroll
      for (int r = 0; r < 4; ++r)
        U1[(size_t)(row0 + r) * N_H + col] = f2bf(acc[i][j][r]);
    }
  }
}

// ---------------------------------------------------------------------------
// Scan1: per (b,h) chain over T (bf16 input); spike BITMASK via ballot.
// Depth-25 double-buffered load batches (~6KB in flight/CU at 2 waves/CU).
// ---------------------------------------------------------------------------
__global__ __launch_bounds__(128) void scan1_kernel(const unsigned short* __restrict__ U1,
                                                    unsigned long long* __restrict__ S1m) {
  int idx  = blockIdx.x * 128 + threadIdx.x;  // b*512 + h
  int b    = idx >> 9, h = idx & 511;
  int lane = threadIdx.x & 63;
  const unsigned short* u = U1 + (size_t)b * T_N * N_H + h;
  unsigned long long* mout = S1m + (size_t)b * T_N * 8 + (h >> 6);
  float p = 0.f, r = 0.f;
  float bufA[25], bufB[25];

  auto load = [&](float* buf, int t0) {
    #pragma unroll
    for (int j = 0; j < 25; ++j) buf[j] = bf2f(u[(size_t)(t0 + j) * N_H]);
  };
  auto proc = [&](const float* buf, int t0) {
    #pragma unroll
    for (int j = 0; j < 25; ++j) {
      p = DECAY_SR * p + buf[j];
      float v = p + r;
      bool sp = (v >= THETA);
      r = DECAY_REF * (r - (sp ? 2.f * THETA : 0.f));
      unsigned long long bal = __ballot(sp);
      if (lane == 0) mout[(size_t)(t0 + j) * 8] = bal;
    }
  };

  load(bufA, 0);
  for (int g = 0; g < 10; ++g) {
    int ta = g * 50, tb = ta + 25;
    load(bufB, tb);
    proc(bufA, ta);
    if (g < 9) load(bufA, tb + 25);
    proc(bufB, tb);
  }
}

// ---------------------------------------------------------------------------
// GEMM2 from bitmask: U2[m][o] = sum_{h: spike} W2[o][h]. Wave per m-row.
// ---------------------------------------------------------------------------
__global__ __launch_bounds__(256) void gemm2_kernel(const unsigned char* __restrict__ S1b,
                                                    const float* __restrict__ W2,
                                                    float* __restrict__ U2) {
  int m    = blockIdx.x * 4 + (threadIdx.x >> 6);
  int lane = threadIdx.x & 63;
  unsigned int byte = S1b[(size_t)m * 64 + lane];
  float a0 = 0.f, a1 = 0.f;
  #pragma unroll
  for (int j = 0; j < 8; ++j) {
    int h = lane * 8 + j;
    float sel = ((byte >> j) & 1u) ? 1.f : 0.f;
    a0 += sel * W2[h];
    a1 += sel * W2[N_H + h];
  }
  #pragma unroll
  for (int off = 32; off >= 1; off >>= 1) {
    a0 += __shfl_down(a0, off);
    a1 += __shfl_down(a1, off);
  }
  if (lane == 0) {
    U2[(size_t)m * 2]     = a0;
    U2[(size_t)m * 2 + 1] = a1;
  }
}

// ---------------------------------------------------------------------------
// Scan2: per-b block; stage u2[b] (500x2) in LDS, lanes 0/1 run the scans.
// ---------------------------------------------------------------------------
__global__ __launch_bounds__(128) void scan2_kernel(const float* __restrict__ U2,
                                                    float* __restrict__ OUT) {
  __shared__ float lu[T_N * 2];
  __shared__ float ls[T_N * 2];
  int b = blockIdx.x;
  const float* src = U2 + (size_t)b * T_N * 2;
  for (int i = threadIdx.x; i < T_N * 2; i += 128) lu[i] = src[i];
  __syncthreads();
  if (threadIdx.x < 2) {
    int o = threadIdx.x;
    float p = 0.f, r = 0.f;
    for (int t = 0; t < T_N; ++t) {
      p = DECAY_SR * p + lu[t * 2 + o];
      float v = p + r;
      float sp = (v >= THETA) ? 1.f : 0.f;
      r = DECAY_REF * (r - 2.f * THETA * sp);
      ls[t * 2 + o] = sp;
    }
  }
  __syncthreads();
  float* dst = OUT + (size_t)b * T_N * 2;
  for (int i = threadIdx.x; i < T_N * 2; i += 128) dst[i] = ls[i];
}

// ---------------------------------------------------------------------------
extern "C" void kernel_launch(void* const* d_in, const int* in_sizes, int n_in,
                              void* d_out, int out_size, void* d_ws, size_t ws_size,
                              hipStream_t stream) {
  const float* X  = (const float*)d_in[0];   // (64,500,1250)
  const float* W1 = (const float*)d_in[1];   // (512,1250)
  const float* W2 = (const float*)d_in[2];   // (2,512)
  float* OUT = (float*)d_out;                // (64,500,2)

  char* ws = (char*)d_ws;
  short*              W1b = (short*)ws;                             //  1,310,720 B
  unsigned short*     U1  = (unsigned short*)(ws + 1310720);        // 32,768,000 B
  unsigned long long* S1m = (unsigned long long*)(ws + 34078720);   //  2,048,000 B
  float*              U2  = (float*)(ws + 36126720);                //    256,000 B
  unsigned long long* Xb  = (unsigned long long*)(ws + 36382720);   //  5,120,000 B

  xpack_kernel<<<dim3(M_N / 4), 256, 0, stream>>>(X, Xb);
  w1cvt_kernel<<<dim3(KP / 256, N_H), 256, 0, stream>>>(W1, W1b);
  gemm1_kernel<<<dim3(N_H / BN, M_N / BM), 256, 0, stream>>>((const unsigned char*)Xb, W1b, U1);
  scan1_kernel<<<dim3((B_N * N_H) / 128), 128, 0, stream>>>(U1, S1m);
  gemm2_kernel<<<dim3(M_N / 4), 256, 0, stream>>>((const unsigned char*)S1m, W2, U2);
  scan2_kernel<<<dim3(B_N), 128, 0, stream>>>(U2, OUT);
}

// Round 9
// 380.045 us; speedup vs baseline: 1.0203x; 1.0203x over previous
//
#include <hip/hip_runtime.h>
#include <hip/hip_bf16.h>
#include <cstdint>
#include <cstddef>

// Problem dims
#define B_N   64
#define T_N   500
#define K_IN  1250
#define KP    1280          // K padded to multiple of 32
#define N_H   512
#define M_N   32000

// GEMM1 tiling: 128 x 128 tile, 4 waves (2x2), wave tile 64x64
#define BM 128
#define BN 128
#define BK 32
#define NT (KP / BK)        // 40
#define XROWB (KP / 8)      // 160 bytes of bits per row

typedef __attribute__((ext_vector_type(8))) short bf16x8;  // 8 bf16 = 4 VGPRs
typedef __attribute__((ext_vector_type(4))) float f32x4;   // MFMA acc

#define DECAY_SR  0.9048374180359595732f   // exp(-1/10)
#define DECAY_REF 0.3678794411714423216f   // exp(-1)
#define THETA 10.0f

__device__ __forceinline__ unsigned short f2bf(float f) {
  __hip_bfloat16 h = __float2bfloat16(f);          // RNE
  return *reinterpret_cast<unsigned short*>(&h);
}
__device__ __forceinline__ float bf2f(unsigned short s) {
  union { uint32_t u; float f; } v; v.u = ((uint32_t)s) << 16; return v.f;
}

// ---------------------------------------------------------------------------
// Pre-pass A: bitpack X (binary spikes) -> Xb [32000][160B].
// ---------------------------------------------------------------------------
__global__ __launch_bounds__(256) void xpack_kernel(const float* __restrict__ X,
                                                    unsigned long long* __restrict__ Xb64) {
  int gw   = (blockIdx.x * 256 + threadIdx.x) >> 6;   // 0..31999 = row
  int lane = threadIdx.x & 63;
  const float* xr = X + (size_t)gw * K_IN;
  unsigned long long* out = Xb64 + (size_t)gw * (XROWB / 8);
  #pragma unroll
  for (int wd = 0; wd < 20; ++wd) {
    int k = wd * 64 + lane;
    float v = (k < K_IN) ? xr[k] : 0.f;
    unsigned long long m = __ballot(v > 0.5f);
    if (lane == 0) out[wd] = m;
  }
}

// ---------------------------------------------------------------------------
// Pre-pass B: W1 (512x1250 fp32) -> W1b (512x1280 bf16, zero-padded tail).
// ---------------------------------------------------------------------------
__global__ __launch_bounds__(256) void w1cvt_kernel(const float* __restrict__ W1,
                                                    short* __restrict__ W1b) {
  int k = blockIdx.x * 256 + threadIdx.x;   // 0..1279
  int n = blockIdx.y;                        // 0..511
  float v = (k < K_IN) ? W1[(size_t)n * K_IN + k] : 0.f;
  W1b[(size_t)n * KP + k] = (short)f2bf(v);
}

// ---------------------------------------------------------------------------
// GEMM1: U1[m][n] = sum_k X[m][k] * W1[n][k]
// 1000 blocks, XCD-chunked swizzle (1000%8==0, bijective): the 4 n-blocks
// sharing an m-strip run on the SAME XCD -> A-bits strip is per-XCD
// L2-resident; W1b (1.25MB) L2-resident everywhere.
// 256 thr = 4 waves (2x2), wave tile 64x64 (4x4 frags, acc=64 VGPR).
// __launch_bounds__(256,4): VGPR<=128 -> 4 waves/SIMD -> 4 blocks/CU
// (LDS 20KB). Simple verified 2-phase dbuf: stage(t+1) via global_load_lds
// -> compute(t) -> __syncthreads (single drain/step); inter-block overlap
// (4 blocks/CU) hides the drain.
// A: bitpacked bytes, per-lane scalar loads prefetched 1 K-step ahead;
// expand via 4KB LDS LUT (byte -> 8 x bf16{0,1}); ~90% of bytes are 0 ->
// LUT reads broadcast (same-address).
// B swizzle slot'=slot^((row>>1)&3) (r4/r6/r8-verified: 0 conflicts).
// k-pairing: k = (lane>>4)*8 + elem, identical A and B (layout-agnostic).
// ---------------------------------------------------------------------------
__global__ __launch_bounds__(256, 4) void gemm1_kernel(const unsigned char* __restrict__ Xb,
                                                       const short* __restrict__ W1b,
                                                       unsigned short* __restrict__ U1) {
  __shared__ short Bs[2][BN * BK];   // 2 x 8 KiB
  __shared__ short LUT[256 * 8];     // 4 KiB
  const int tid  = threadIdx.x;
  // XCD-chunked bijective swizzle: d%8 = hardware XCD; consecutive logical
  // ids within an XCD share an m-strip (n fastest).
  const int d       = blockIdx.x;          // 0..999
  const int logical = (d & 7) * 125 + (d >> 3);
  const int bn      = (logical & 3) * BN;
  const int bm      = (logical >> 2) * BM;
  const int w    = tid >> 6;
  const int lane = tid & 63;
  const int wr   = w >> 1;                 // m half
  const int wc   = w & 1;                  // n half
  const int lrow = lane & 15;
  const int lgrp = lane >> 4;
  const int lsw  = lgrp ^ ((lrow >> 1) & 3);

  // ---- build LUT (256 entries x 16B) ----
  {
    int b = tid;
    uint32_t w0 = ((b & 1)  ? 0x3F80u : 0u) | ((b & 2)  ? 0x3F800000u : 0u);
    uint32_t w1 = ((b & 4)  ? 0x3F80u : 0u) | ((b & 8)  ? 0x3F800000u : 0u);
    uint32_t w2 = ((b & 16) ? 0x3F80u : 0u) | ((b & 32) ? 0x3F800000u : 0u);
    uint32_t w3 = ((b & 64) ? 0x3F80u : 0u) | ((b & 128)? 0x3F800000u : 0u);
    uint4 q; q.x = w0; q.y = w1; q.z = w2; q.w = w3;
    *(uint4*)&LUT[b * 8] = q;
  }

  f32x4 acc[4][4];
  #pragma unroll
  for (int i = 0; i < 4; ++i)
    #pragma unroll
    for (int j = 0; j < 4; ++j)
      acc[i][j] = (f32x4){0.f, 0.f, 0.f, 0.f};

  const int brow16 = lane >> 2;
  const int bslp   = lane & 3;
  const unsigned char* xbase = Xb + (size_t)(bm + wr * 64 + lrow) * XROWB + lgrp;

  auto stage = [&](int buf, int t) {
    int k0 = t * BK;
    #pragma unroll
    for (int c = 0; c < 2; ++c) {
      int ch = w * 2 + c;                         // 0..7
      int nl = ch * 16 + brow16;                  // local col 0..127
      int ss = bslp ^ ((nl >> 1) & 3);            // pre-swizzled source slot
      const short* src = W1b + (size_t)(bn + nl) * KP + k0 + ss * 8;
      __builtin_amdgcn_global_load_lds(
          (const __attribute__((address_space(1))) void*)src,
          (__attribute__((address_space(3))) void*)&Bs[buf][ch * 16 * BK], 16, 0, 0);
    }
  };

  // prologue: stage tile 0, prefetch A bytes for t=0
  stage(0, 0);
  unsigned char c0 = xbase[0];
  unsigned char c1 = xbase[16 * XROWB];
  unsigned char c2 = xbase[32 * XROWB];
  unsigned char c3 = xbase[48 * XROWB];
  __syncthreads();

  int pb = 0;
  for (int t = 0; t < NT; ++t) {
    unsigned char n0 = c0, n1 = c1, n2 = c2, n3 = c3;
    if (t + 1 < NT) {
      stage(pb ^ 1, t + 1);                       // DMA next tile
      const unsigned char* xn = xbase + (t + 1) * 4;
      n0 = xn[0];
      n1 = xn[16 * XROWB];
      n2 = xn[32 * XROWB];
      n3 = xn[48 * XROWB];
    }
    // A frags via LUT (broadcast-dominated), B frags from LDS
    bf16x8 af[4];
    af[0] = *(const bf16x8*)&LUT[(int)c0 * 8];
    af[1] = *(const bf16x8*)&LUT[(int)c1 * 8];
    af[2] = *(const bf16x8*)&LUT[(int)c2 * 8];
    af[3] = *(const bf16x8*)&LUT[(int)c3 * 8];
    bf16x8 bv[4];
    #pragma unroll
    for (int j = 0; j < 4; ++j) {
      int r = wc * 64 + j * 16 + lrow;
      bv[j] = *(const bf16x8*)&Bs[pb][r * BK + lsw * 8];
    }
    #pragma unroll
    for (int i = 0; i < 4; ++i)
      #pragma unroll
      for (int j = 0; j < 4; ++j)
        acc[i][j] = __builtin_amdgcn_mfma_f32_16x16x32_bf16(af[i], bv[j], acc[i][j], 0, 0, 0);
    __syncthreads();                              // single drain per K-step
    pb ^= 1;
    c0 = n0; c1 = n1; c2 = n2; c3 = n3;
  }

  // ---- epilogue: C/D map col=lane&15, row=(lane>>4)*4+reg; U1 bf16 ----
  #pragma unroll
  for (int i = 0; i < 4; ++i) {
    int row0 = bm + wr * 64 + i * 16 + lgrp * 4;
    #pragma unroll
    for (int j = 0; j < 4; ++j) {
      int col = bn + wc * 64 + j * 16 + lrow;
      #pragma unroll
      for (int r = 0; r < 4; ++r)
        U1[(size_t)(row0 + r) * N_H + col] = f2bf(acc[i][j][r]);
    }
  }
}

// ---------------------------------------------------------------------------
// Scan1: per (b,h) chain over T (bf16 input); spike BITMASK via ballot.
// Depth-25 double-buffered load batches.
// ---------------------------------------------------------------------------
__global__ __launch_bounds__(128) void scan1_kernel(const unsigned short* __restrict__ U1,
                                                    unsigned long long* __restrict__ S1m) {
  int idx  = blockIdx.x * 128 + threadIdx.x;  // b*512 + h
  int b    = idx >> 9, h = idx & 511;
  int lane = threadIdx.x & 63;
  const unsigned short* u = U1 + (size_t)b * T_N * N_H + h;
  unsigned long long* mout = S1m + (size_t)b * T_N * 8 + (h >> 6);
  float p = 0.f, r = 0.f;
  float bufA[25], bufB[25];

  auto load = [&](float* buf, int t0) {
    #pragma unroll
    for (int j = 0; j < 25; ++j) buf[j] = bf2f(u[(size_t)(t0 + j) * N_H]);
  };
  auto proc = [&](const float* buf, int t0) {
    #pragma unroll
    for (int j = 0; j < 25; ++j) {
      p = DECAY_SR * p + buf[j];
      float v = p + r;
      bool sp = (v >= THETA);
      r = DECAY_REF * (r - (sp ? 2.f * THETA : 0.f));
      unsigned long long bal = __ballot(sp);
      if (lane == 0) mout[(size_t)(t0 + j) * 8] = bal;
    }
  };

  load(bufA, 0);
  for (int g = 0; g < 10; ++g) {
    int ta = g * 50, tb = ta + 25;
    load(bufB, tb);
    proc(bufA, ta);
    if (g < 9) load(bufA, tb + 25);
    proc(bufB, tb);
  }
}

// ---------------------------------------------------------------------------
// GEMM2 from bitmask: U2[m][o] = sum_{h: spike} W2[o][h]. Wave per m-row.
// ---------------------------------------------------------------------------
__global__ __launch_bounds__(256) void gemm2_kernel(const unsigned char* __restrict__ S1b,
                                                    const float* __restrict__ W2,
                                                    float* __restrict__ U2) {
  int m    = blockIdx.x * 4 + (threadIdx.x >> 6);
  int lane = threadIdx.x & 63;
  unsigned int byte = S1b[(size_t)m * 64 + lane];
  float a0 = 0.f, a1 = 0.f;
  #pragma unroll
  for (int j = 0; j < 8; ++j) {
    int h = lane * 8 + j;
    float sel = ((byte >> j) & 1u) ? 1.f : 0.f;
    a0 += sel * W2[h];
    a1 += sel * W2[N_H + h];
  }
  #pragma unroll
  for (int off = 32; off >= 1; off >>= 1) {
    a0 += __shfl_down(a0, off);
    a1 += __shfl_down(a1, off);
  }
  if (lane == 0) {
    U2[(size_t)m * 2]     = a0;
    U2[(size_t)m * 2 + 1] = a1;
  }
}

// ---------------------------------------------------------------------------
// Scan2: per-b block; stage u2[b] (500x2) in LDS, lanes 0/1 run the scans.
// ---------------------------------------------------------------------------
__global__ __launch_bounds__(128) void scan2_kernel(const float* __restrict__ U2,
                                                    float* __restrict__ OUT) {
  __shared__ float lu[T_N * 2];
  __shared__ float ls[T_N * 2];
  int b = blockIdx.x;
  const float* src = U2 + (size_t)b * T_N * 2;
  for (int i = threadIdx.x; i < T_N * 2; i += 128) lu[i] = src[i];
  __syncthreads();
  if (threadIdx.x < 2) {
    int o = threadIdx.x;
    float p = 0.f, r = 0.f;
    for (int t = 0; t < T_N; ++t) {
      p = DECAY_SR * p + lu[t * 2 + o];
      float v = p + r;
      float sp = (v >= THETA) ? 1.f : 0.f;
      r = DECAY_REF * (r - 2.f * THETA * sp);
      ls[t * 2 + o] = sp;
    }
  }
  __syncthreads();
  float* dst = OUT + (size_t)b * T_N * 2;
  for (int i = threadIdx.x; i < T_N * 2; i += 128) dst[i] = ls[i];
}

// ---------------------------------------------------------------------------
extern "C" void kernel_launch(void* const* d_in, const int* in_sizes, int n_in,
                              void* d_out, int out_size, void* d_ws, size_t ws_size,
                              hipStream_t stream) {
  const float* X  = (const float*)d_in[0];   // (64,500,1250)
  const float* W1 = (const float*)d_in[1];   // (512,1250)
  const float* W2 = (const float*)d_in[2];   // (2,512)
  float* OUT = (float*)d_out;                // (64,500,2)

  char* ws = (char*)d_ws;
  short*              W1b = (short*)ws;                             //  1,310,720 B
  unsigned short*     U1  = (unsigned short*)(ws + 1310720);        // 32,768,000 B
  unsigned long long* S1m = (unsigned long long*)(ws + 34078720);   //  2,048,000 B
  float*              U2  = (float*)(ws + 36126720);                //    256,000 B
  unsigned long long* Xb  = (unsigned long long*)(ws + 36382720);   //  5,120,000 B

  xpack_kernel<<<dim3(M_N / 4), 256, 0, stream>>>(X, Xb);
  w1cvt_kernel<<<dim3(KP / 256, N_H), 256, 0, stream>>>(W1, W1b);
  gemm1_kernel<<<dim3((M_N / BM) * (N_H / BN)), 256, 0, stream>>>((const unsigned char*)Xb, W1b, U1);
  scan1_kernel<<<dim3((B_N * N_H) / 128), 128, 0, stream>>>(U1, S1m);
  gemm2_kernel<<<dim3(M_N / 4), 256, 0, stream>>>((const unsigned char*)S1m, W2, U2);
  scan2_kernel<<<dim3(B_N), 128, 0, stream>>>(U2, OUT);
}